// Round 16
// baseline (80.242 us; speedup 1.0000x reference)
//
#include <hip/hip_runtime.h>
#include <hip/hip_bf16.h>

typedef __attribute__((ext_vector_type(8))) short short8;   // 8 bf16 = 4 VGPR
typedef __attribute__((ext_vector_type(4))) float f32x4;

// Problem dims (fixed by reference)
constexpr int Bb = 8;
constexpr int Dd = 64;
constexpr int Tt = 8192;
constexpr int Kk = 1024;
constexpr int BT = Bb * Tt;            // 65536 rows
constexpr int NTOT = Bb * Dd * Tt;     // 4194304 elements

// Output layout (float32): [codes BT][quantized NTOT][loss 1]
constexpr int OUT_Q_OFF = BT;
constexpr int OUT_LOSS_OFF = BT + NTOT;

// Workspace layout (bytes)
constexpr size_t WS_PREC_OFF  = 0;                        // float[K]       4KB
constexpr size_t WS_PART_OFF  = WS_PREC_OFF + 4096;       // float[1024]    4KB
constexpr size_t WS_EH_OFF    = WS_PART_OFF + 4096;       // bf16[K*D] x3
constexpr size_t WS_EM_OFF    = WS_EH_OFF + (size_t)Kk * Dd * 2;
constexpr size_t WS_EL_OFF    = WS_EM_OFF + (size_t)Kk * Dd * 2;

// ---- bf16 helpers (RNE, matches numpy/jax) ----
__device__ inline ushort rne_bf16(float v) {
    unsigned u = __float_as_uint(v);
    return (ushort)((u + 0x7FFFu + ((u >> 16) & 1u)) >> 16);
}
__device__ inline float bf16f(ushort h) { return __uint_as_float(((unsigned)h) << 16); }

// ---------------- Kernel PS: fused prec + 3-way bf16 split ----------------
__global__ void __launch_bounds__(256) prep_kernel(const float* __restrict__ cb,
                                                   float* __restrict__ prec,
                                                   ushort* __restrict__ eh,
                                                   ushort* __restrict__ em,
                                                   ushort* __restrict__ el) {
    const int k = blockIdx.x * 256 + threadIdx.x;   // grid = 4 blocks -> k in [0,1024)
    const float4* row = reinterpret_cast<const float4*>(cb + (size_t)k * Dd);
    float4 v[16];
    float s = 0.f;
#pragma unroll
    for (int i = 0; i < 16; ++i) {
        v[i] = row[i];
        s = fmaf(v[i].x, v[i].x, s); s = fmaf(v[i].y, v[i].y, s);
        s = fmaf(v[i].z, v[i].z, s); s = fmaf(v[i].w, v[i].w, s);
    }
    prec[k] = s;
#pragma unroll
    for (int g = 0; g < 8; ++g) {
        float vals[8] = {v[2*g].x, v[2*g].y, v[2*g].z, v[2*g].w,
                         v[2*g+1].x, v[2*g+1].y, v[2*g+1].z, v[2*g+1].w};
        short8 hv, mv, lv;
#pragma unroll
        for (int j = 0; j < 8; ++j) {
            float x = vals[j];
            ushort h = rne_bf16(x);  float hf = bf16f(h);
            float r1 = x - hf;       ushort m = rne_bf16(r1); float mf = bf16f(m);
            float r2 = r1 - mf;      ushort l = rne_bf16(r2);
            hv[j] = (short)h; mv[j] = (short)m; lv[j] = (short)l;
        }
        const size_t base = (size_t)k * 64 + g * 8;
        *reinterpret_cast<short8*>(eh + base) = hv;
        *reinterpret_cast<short8*>(em + base) = mv;
        *reinterpret_cast<short8*>(el + base) = lv;
    }
}

// ---------------- Kernel A: fused split-MFMA GEMM + argmin + quant + loss ----
// r15 fused structure (77.5us total), one change: each rf's 12-deep dependent
// MFMA chain is split by d-step into accP (d0..31) + accQ (d32..63) -> chain
// depth 6, 8 independent chains/wave (16/SIMD at 2 waves). Epilogue:
// dot = accP+accQ (extra rounding at |dot|~5e-3, ulp ~6e-10 — inside the
// established ~1e-9 band vs the 7.6e-6 reference tie grid), then the
// reference-order score s = fp32(t1 - 2*dot), t1 = fp32(zsq+esq);
// tie -> lowest k everywhere.
constexpr int TM = 64;              // rows per block
constexpr int NKT = Kk / 64;        // 16 k-tiles

__global__ void __launch_bounds__(256, 2) mfma_argmin_kernel(
    const float* __restrict__ z, const float* __restrict__ cb,
    const ushort* __restrict__ eh, const ushort* __restrict__ em,
    const ushort* __restrict__ el,
    const float* __restrict__ prec, float* __restrict__ out,
    float* __restrict__ partials)
{
    // z tile, 3 planes, swizzled: [split][row][d], row stride 128B, byte ^= (row&7)<<4
    __shared__ __align__(16) ushort z_lds[3 * 64 * 64];   // 24 KB
    __shared__ float zsq_part[4][64];                     // reused as 256-red
    __shared__ float zsq_lds[64];
    __shared__ float red_v[4][64];
    __shared__ int   red_i[4][64];
    __shared__ int   codes_lds[64];

    const int tid = threadIdx.x;
    const int lane = tid & 63;
    const int w = tid >> 6;                 // wave 0..3 -> k-slice w*16..+16
    const int row0 = blockIdx.x * TM;
    const int b = row0 >> 13;
    const int t0 = row0 & (Tt - 1);

    // ---- stage z: read [d][t] coalesced, 3-way split, write transposed+swizzled
    {
        const int tt = tid & 63;            // row within tile
        const int dg = tid >> 6;            // d-group: d = dg*16 .. +16
        const float* zp = z + (size_t)b * (Dd * Tt) + (size_t)(dg * 16) * Tt + (t0 + tt);
        float vals[16];
        float psum = 0.f;
#pragma unroll
        for (int i = 0; i < 16; ++i) {
            float v = zp[(size_t)i * Tt];
            vals[i] = v;
            psum = fmaf(v, v, psum);
        }
        zsq_part[dg][tt] = psum;
#pragma unroll
        for (int g = 0; g < 2; ++g) {
            short8 hv, mv, lv;
#pragma unroll
            for (int j = 0; j < 8; ++j) {
                float v = vals[g * 8 + j];
                ushort h = rne_bf16(v);  float hf = bf16f(h);
                float r1 = v - hf;       ushort m = rne_bf16(r1); float mf = bf16f(m);
                float r2 = r1 - mf;      ushort l = rne_bf16(r2);
                hv[j] = (short)h; mv[j] = (short)m; lv[j] = (short)l;
            }
            const int byte_in_row = dg * 32 + g * 16;     // d0*2
            const int sw = tt * 128 + (byte_in_row ^ ((tt & 7) << 4));
            *reinterpret_cast<short8*>((char*)z_lds + 0 * 8192 + sw) = hv;
            *reinterpret_cast<short8*>((char*)z_lds + 1 * 8192 + sw) = mv;
            *reinterpret_cast<short8*>((char*)z_lds + 2 * 8192 + sw) = lv;
        }
    }
    __syncthreads();
    if (tid < 64)
        zsq_lds[tid] = ((zsq_part[0][tid] + zsq_part[1][tid]) + zsq_part[2][tid]) + zsq_part[3][tid];
    __syncthreads();

    // ---- A fragments into registers (once)
    short8 A[3][2][4];   // [plane][dstep][rf]
#pragma unroll
    for (int sA = 0; sA < 3; ++sA)
#pragma unroll
        for (int ds = 0; ds < 2; ++ds)
#pragma unroll
            for (int rf = 0; rf < 4; ++rf) {
                const int row = rf * 16 + (lane & 15);
                const int dby = ds * 64 + ((lane >> 4) * 16);
                A[sA][ds][rf] = *reinterpret_cast<const short8*>(
                    (char*)z_lds + sA * 8192 + row * 128 + (dby ^ ((row & 7) << 4)));
            }

    // per-lane row-set zsq: row = rf*16 + (lane>>4)*4 + j
    float zsq_r[16];
#pragma unroll
    for (int rf = 0; rf < 4; ++rf)
#pragma unroll
        for (int j = 0; j < 4; ++j)
            zsq_r[rf * 4 + j] = zsq_lds[rf * 16 + (lane >> 4) * 4 + j];

    float bestv[16];
    int   besti[16];
#pragma unroll
    for (int i = 0; i < 16; ++i) { bestv[i] = 3.4e38f; besti[i] = 0; }

    const int kl = lane & 15;
    const int d0 = (lane >> 4) * 8;

    // B fragment loads from global (r9 form): current + next-tile prefetch
    short8 Bc[6];      // [p*2+ds]
    float esqc;
    {
        const size_t kg = (size_t)(w * 16 + kl);
        const size_t base = kg * 64 + d0;
        Bc[0] = *reinterpret_cast<const short8*>(eh + base);
        Bc[1] = *reinterpret_cast<const short8*>(eh + base + 32);
        Bc[2] = *reinterpret_cast<const short8*>(em + base);
        Bc[3] = *reinterpret_cast<const short8*>(em + base + 32);
        Bc[4] = *reinterpret_cast<const short8*>(el + base);
        Bc[5] = *reinterpret_cast<const short8*>(el + base + 32);
        esqc = prec[kg];
    }

    for (int kt = 0; kt < NKT; ++kt) {
        short8 Bn[6];
        float esqn = 0.f;
        if (kt + 1 < NKT) {
            const size_t kg = (size_t)((kt + 1) * 64 + w * 16 + kl);
            const size_t base = kg * 64 + d0;
            Bn[0] = *reinterpret_cast<const short8*>(eh + base);
            Bn[1] = *reinterpret_cast<const short8*>(eh + base + 32);
            Bn[2] = *reinterpret_cast<const short8*>(em + base);
            Bn[3] = *reinterpret_cast<const short8*>(em + base + 32);
            Bn[4] = *reinterpret_cast<const short8*>(el + base);
            Bn[5] = *reinterpret_cast<const short8*>(el + base + 32);
            esqn = prec[kg];
        }

        // accP: d0..31 (ds=0), accQ: d32..63 (ds=1) — 8 chains of depth 6.
        f32x4 accP[4], accQ[4];
#pragma unroll
        for (int rf = 0; rf < 4; ++rf) {
            accP[rf] = (f32x4){0.f, 0.f, 0.f, 0.f};
            accQ[rf] = (f32x4){0.f, 0.f, 0.f, 0.f};
        }

        // pass p: (A-plane, B-slot): (0,eh),(0,em),(0,el),(1,eh),(1,em),(2,eh)
#pragma unroll
        for (int p = 0; p < 6; ++p) {
            const int pa = (p < 3) ? 0 : (p < 5 ? 1 : 2);
            const int bs = (p < 3) ? p : (p < 5 ? p - 3 : 0);
#pragma unroll
            for (int rf = 0; rf < 4; ++rf)
                accP[rf] = __builtin_amdgcn_mfma_f32_16x16x32_bf16(A[pa][0][rf], Bc[bs * 2 + 0], accP[rf], 0, 0, 0);
#pragma unroll
            for (int rf = 0; rf < 4; ++rf)
                accQ[rf] = __builtin_amdgcn_mfma_f32_16x16x32_bf16(A[pa][1][rf], Bc[bs * 2 + 1], accQ[rf], 0, 0, 0);
        }

        // epilogue: dot = P+Q, then reference-order score; tie -> lowest k
        const int kglob = kt * 64 + w * 16 + kl;
#pragma unroll
        for (int rf = 0; rf < 4; ++rf)
#pragma unroll
            for (int j = 0; j < 4; ++j) {
                const float dot = accP[rf][j] + accQ[rf][j];
                const float t1 = zsq_r[rf * 4 + j] + esqc;       // round(zsq+esq)
                const float s = fmaf(-2.f, dot, t1);             // round(t1-2dot)
                if (s < bestv[rf * 4 + j]) { bestv[rf * 4 + j] = s; besti[rf * 4 + j] = kglob; }
            }

        if (kt + 1 < NKT) {
#pragma unroll
            for (int i = 0; i < 6; ++i) Bc[i] = Bn[i];
            esqc = esqn;
        }
    }

    // ---- in-wave reduce over the 16 k-slots (lane&15) per row, tie -> lower k
#pragma unroll
    for (int i = 0; i < 16; ++i) {
#pragma unroll
        for (int m = 1; m < 16; m <<= 1) {
            const float ov = __shfl_xor(bestv[i], m, 16);
            const int   oi = __shfl_xor(besti[i], m, 16);
            if (ov < bestv[i] || (ov == bestv[i] && oi < besti[i])) {
                bestv[i] = ov; besti[i] = oi;
            }
        }
    }
    if ((lane & 15) == 0) {
#pragma unroll
        for (int rf = 0; rf < 4; ++rf)
#pragma unroll
            for (int j = 0; j < 4; ++j) {
                const int row = rf * 16 + (lane >> 4) * 4 + j;
                red_v[w][row] = bestv[rf * 4 + j];
                red_i[w][row] = besti[rf * 4 + j];
            }
    }
    __syncthreads();
    if (tid < 64) {
        float bv = red_v[0][tid];
        int   bi = red_i[0][tid];
#pragma unroll
        for (int s2 = 1; s2 < 4; ++s2) {
            const float v = red_v[s2][tid];
            const int   i = red_i[s2][tid];
            if (v < bv || (v == bv && i < bi)) { bv = v; bi = i; }
        }
        codes_lds[tid] = bi;
        out[row0 + tid] = (float)bi;
    }
    __syncthreads();

    // ---- fused quant + loss tail ----
    // thread (tt, dg): row tt, dims d = dg*16 .. dg*16+15
    {
        const int tt = tid & 63;
        const int dg = tid >> 6;
        const int code = codes_lds[tt];
        const float4* crow = reinterpret_cast<const float4*>(cb + (size_t)code * Dd + dg * 16);
        float4 q4[4];
#pragma unroll
        for (int i = 0; i < 4; ++i) q4[i] = crow[i];
        const float qf[16] = {q4[0].x, q4[0].y, q4[0].z, q4[0].w,
                              q4[1].x, q4[1].y, q4[1].z, q4[1].w,
                              q4[2].x, q4[2].y, q4[2].z, q4[2].w,
                              q4[3].x, q4[3].y, q4[3].z, q4[3].w};
        float* obase = out + OUT_Q_OFF + (size_t)b * (Dd * Tt) + (size_t)(dg * 16) * Tt + (t0 + tt);
        float lacc = 0.f;
#pragma unroll
        for (int g = 0; g < 2; ++g) {
            const int sw = tt * 128 + ((dg * 32 + g * 16) ^ ((tt & 7) << 4));
            const short8 zh8 = *reinterpret_cast<const short8*>((char*)z_lds + 0 * 8192 + sw);
            const short8 zm8 = *reinterpret_cast<const short8*>((char*)z_lds + 1 * 8192 + sw);
            const short8 zl8 = *reinterpret_cast<const short8*>((char*)z_lds + 2 * 8192 + sw);
#pragma unroll
            for (int j = 0; j < 8; ++j) {
                // z reconstructed from its 3-way split: err <= 2^-27|z| (loss-only)
                const float zv = (bf16f((ushort)zh8[j]) + bf16f((ushort)zm8[j])) + bf16f((ushort)zl8[j]);
                const float qv = qf[g * 8 + j];
                const float diff = qv - zv;
                lacc = fmaf(diff, diff, lacc);
                obase[(size_t)(g * 8 + j) * Tt] = qv;   // exact fp32 codebook value
            }
        }
        // block reduce 256 -> 1 (reuse zsq_part as flat float[256])
        float* red256 = &zsq_part[0][0];
        red256[tid] = lacc;
        __syncthreads();
#pragma unroll
        for (int s = 128; s > 0; s >>= 1) {
            if (tid < s) red256[tid] += red256[tid + s];
            __syncthreads();
        }
        if (tid == 0) partials[blockIdx.x] = red256[0];
    }
}

// ---------------- Kernel C: final loss reduce (1024 partials) ----------------
__global__ void __launch_bounds__(256) loss_kernel(const float* __restrict__ partials,
                                                   float* __restrict__ out) {
    __shared__ float red[256];
    const int t = threadIdx.x;
    red[t] = ((partials[t] + partials[t + 256]) + partials[t + 512]) + partials[t + 768];
    __syncthreads();
#pragma unroll
    for (int s = 128; s > 0; s >>= 1) {
        if (t < s) red[t] += red[t + s];
        __syncthreads();
    }
    if (t == 0)
        out[OUT_LOSS_OFF] = red[0] * (1.0f / (float)NTOT);
}

extern "C" void kernel_launch(void* const* d_in, const int* in_sizes, int n_in,
                              void* d_out, int out_size, void* d_ws, size_t ws_size,
                              hipStream_t stream) {
    const float* z = (const float*)d_in[0];
    const float* cb = (const float*)d_in[1];
    float* out = (float*)d_out;

    char* ws = (char*)d_ws;
    float* prec = (float*)(ws + WS_PREC_OFF);
    float* partials = (float*)(ws + WS_PART_OFF);
    ushort* eh = (ushort*)(ws + WS_EH_OFF);
    ushort* em = (ushort*)(ws + WS_EM_OFF);
    ushort* el = (ushort*)(ws + WS_EL_OFF);

    prep_kernel<<<Kk / 256, 256, 0, stream>>>(cb, prec, eh, em, el);
    mfma_argmin_kernel<<<BT / TM, 256, 0, stream>>>(z, cb, eh, em, el, prec, out, partials);
    loss_kernel<<<1, 256, 0, stream>>>(partials, out);
}

// Round 17
// 76.807 us; speedup vs baseline: 1.0447x; 1.0447x over previous
//
#include <hip/hip_runtime.h>
#include <hip/hip_bf16.h>

typedef __attribute__((ext_vector_type(8))) short short8;   // 8 bf16 = 4 VGPR
typedef __attribute__((ext_vector_type(4))) float f32x4;

// Problem dims (fixed by reference)
constexpr int Bb = 8;
constexpr int Dd = 64;
constexpr int Tt = 8192;
constexpr int Kk = 1024;
constexpr int BT = Bb * Tt;            // 65536 rows
constexpr int NTOT = Bb * Dd * Tt;     // 4194304 elements

// Output layout (float32): [codes BT][quantized NTOT][loss 1]
constexpr int OUT_Q_OFF = BT;
constexpr int OUT_LOSS_OFF = BT + NTOT;

// Workspace layout (bytes)
constexpr size_t WS_PREC_OFF  = 0;                        // float[K]       4KB
constexpr size_t WS_PART_OFF  = WS_PREC_OFF + 4096;       // float[1024]    4KB
constexpr size_t WS_EI_OFF    = WS_PART_OFF + 4096;       // bf16[K][3][64] interleaved, 384KB

// ---- bf16 helpers (RNE, matches numpy/jax) ----
__device__ inline ushort rne_bf16(float v) {
    unsigned u = __float_as_uint(v);
    return (ushort)((u + 0x7FFFu + ((u >> 16) & 1u)) >> 16);
}
__device__ inline float bf16f(ushort h) { return __uint_as_float(((unsigned)h) << 16); }

// ---------------- Kernel PS: fused prec + 3-way bf16 split (interleaved) ----
// Planes stored interleaved per k: ei[k*192 + plane*64 + d] so the main
// kernel's 6 B-fragment loads share ONE base + immediate offsets.
__global__ void __launch_bounds__(256) prep_kernel(const float* __restrict__ cb,
                                                   float* __restrict__ prec,
                                                   ushort* __restrict__ ei) {
    const int k = blockIdx.x * 256 + threadIdx.x;   // grid = 4 blocks -> k in [0,1024)
    const float4* row = reinterpret_cast<const float4*>(cb + (size_t)k * Dd);
    float4 v[16];
    float s = 0.f;
#pragma unroll
    for (int i = 0; i < 16; ++i) {
        v[i] = row[i];
        s = fmaf(v[i].x, v[i].x, s); s = fmaf(v[i].y, v[i].y, s);
        s = fmaf(v[i].z, v[i].z, s); s = fmaf(v[i].w, v[i].w, s);
    }
    prec[k] = s;
#pragma unroll
    for (int g = 0; g < 8; ++g) {
        float vals[8] = {v[2*g].x, v[2*g].y, v[2*g].z, v[2*g].w,
                         v[2*g+1].x, v[2*g+1].y, v[2*g+1].z, v[2*g+1].w};
        short8 hv, mv, lv;
#pragma unroll
        for (int j = 0; j < 8; ++j) {
            float x = vals[j];
            ushort h = rne_bf16(x);  float hf = bf16f(h);
            float r1 = x - hf;       ushort m = rne_bf16(r1); float mf = bf16f(m);
            float r2 = r1 - mf;      ushort l = rne_bf16(r2);
            hv[j] = (short)h; mv[j] = (short)m; lv[j] = (short)l;
        }
        const size_t base = (size_t)k * 192 + g * 8;
        *reinterpret_cast<short8*>(ei + base + 0)   = hv;   // plane h
        *reinterpret_cast<short8*>(ei + base + 64)  = mv;   // plane m
        *reinterpret_cast<short8*>(ei + base + 128) = lv;   // plane l
    }
}

// ---------------- Kernel A: fused split-MFMA GEMM + argmin + quant + loss ----
// EXACTLY the r15 structure (best measured: 77.5us total): r9 k-loop with
// Bc/Bn prefetch, 6-pass split MFMA in the same order, reference-order fp32
// score s = fp32(t1 - 2*dot), t1 = fp32(zsq+esq), tie -> lowest k; fused
// quant+loss tail (z reconstructed from its 3-way split, err ~2^-27|z|,
// loss-only). Changes vs r15: B planes interleaved -> each tile's 6 B loads
// are ONE base + imm offsets {0,64,128,192,256,320}. (r16's accP/Q chain
// split regressed: chain depth was not the stall; reverted.)
constexpr int TM = 64;              // rows per block
constexpr int NKT = Kk / 64;        // 16 k-tiles

__global__ void __launch_bounds__(256, 2) mfma_argmin_kernel(
    const float* __restrict__ z, const float* __restrict__ cb,
    const ushort* __restrict__ ei,
    const float* __restrict__ prec, float* __restrict__ out,
    float* __restrict__ partials)
{
    // z tile, 3 planes, swizzled: [split][row][d], row stride 128B, byte ^= (row&7)<<4
    __shared__ __align__(16) ushort z_lds[3 * 64 * 64];   // 24 KB
    __shared__ float zsq_part[4][64];                     // reused as 256-red
    __shared__ float zsq_lds[64];
    __shared__ float red_v[4][64];
    __shared__ int   red_i[4][64];
    __shared__ int   codes_lds[64];

    const int tid = threadIdx.x;
    const int lane = tid & 63;
    const int w = tid >> 6;                 // wave 0..3 -> k-slice w*16..+16
    const int row0 = blockIdx.x * TM;
    const int b = row0 >> 13;
    const int t0 = row0 & (Tt - 1);

    // ---- stage z: read [d][t] coalesced, 3-way split, write transposed+swizzled
    {
        const int tt = tid & 63;            // row within tile
        const int dg = tid >> 6;            // d-group: d = dg*16 .. +16
        const float* zp = z + (size_t)b * (Dd * Tt) + (size_t)(dg * 16) * Tt + (t0 + tt);
        float vals[16];
        float psum = 0.f;
#pragma unroll
        for (int i = 0; i < 16; ++i) {
            float v = zp[(size_t)i * Tt];
            vals[i] = v;
            psum = fmaf(v, v, psum);
        }
        zsq_part[dg][tt] = psum;
#pragma unroll
        for (int g = 0; g < 2; ++g) {
            short8 hv, mv, lv;
#pragma unroll
            for (int j = 0; j < 8; ++j) {
                float v = vals[g * 8 + j];
                ushort h = rne_bf16(v);  float hf = bf16f(h);
                float r1 = v - hf;       ushort m = rne_bf16(r1); float mf = bf16f(m);
                float r2 = r1 - mf;      ushort l = rne_bf16(r2);
                hv[j] = (short)h; mv[j] = (short)m; lv[j] = (short)l;
            }
            const int byte_in_row = dg * 32 + g * 16;     // d0*2
            const int sw = tt * 128 + (byte_in_row ^ ((tt & 7) << 4));
            *reinterpret_cast<short8*>((char*)z_lds + 0 * 8192 + sw) = hv;
            *reinterpret_cast<short8*>((char*)z_lds + 1 * 8192 + sw) = mv;
            *reinterpret_cast<short8*>((char*)z_lds + 2 * 8192 + sw) = lv;
        }
    }
    __syncthreads();
    if (tid < 64)
        zsq_lds[tid] = ((zsq_part[0][tid] + zsq_part[1][tid]) + zsq_part[2][tid]) + zsq_part[3][tid];
    __syncthreads();

    // ---- A fragments into registers (once)
    short8 A[3][2][4];   // [plane][dstep][rf]
#pragma unroll
    for (int sA = 0; sA < 3; ++sA)
#pragma unroll
        for (int ds = 0; ds < 2; ++ds)
#pragma unroll
            for (int rf = 0; rf < 4; ++rf) {
                const int row = rf * 16 + (lane & 15);
                const int dby = ds * 64 + ((lane >> 4) * 16);
                A[sA][ds][rf] = *reinterpret_cast<const short8*>(
                    (char*)z_lds + sA * 8192 + row * 128 + (dby ^ ((row & 7) << 4)));
            }

    // per-lane row-set zsq: row = rf*16 + (lane>>4)*4 + j
    float zsq_r[16];
#pragma unroll
    for (int rf = 0; rf < 4; ++rf)
#pragma unroll
        for (int j = 0; j < 4; ++j)
            zsq_r[rf * 4 + j] = zsq_lds[rf * 16 + (lane >> 4) * 4 + j];

    float bestv[16];
    int   besti[16];
#pragma unroll
    for (int i = 0; i < 16; ++i) { bestv[i] = 3.4e38f; besti[i] = 0; }

    const int kl = lane & 15;
    const int d16b = (lane >> 4) * 16;      // byte offset of this lane's d-chunk

    // B fragment loads: ONE base per tile + imm offsets.
    // Bc[p*2+ds] = plane p (h,m,l), dstep ds -> imm = p*128 + ds*64.
    short8 Bc[6];
    float esqc;
    {
        const size_t kg = (size_t)(w * 16 + kl);
        const char* pb = (const char*)ei + kg * 384 + d16b;
        Bc[0] = *reinterpret_cast<const short8*>(pb + 0);
        Bc[1] = *reinterpret_cast<const short8*>(pb + 64);
        Bc[2] = *reinterpret_cast<const short8*>(pb + 128);
        Bc[3] = *reinterpret_cast<const short8*>(pb + 192);
        Bc[4] = *reinterpret_cast<const short8*>(pb + 256);
        Bc[5] = *reinterpret_cast<const short8*>(pb + 320);
        esqc = prec[kg];
    }

    for (int kt = 0; kt < NKT; ++kt) {
        short8 Bn[6];
        float esqn = 0.f;
        if (kt + 1 < NKT) {
            const size_t kg = (size_t)((kt + 1) * 64 + w * 16 + kl);
            const char* pb = (const char*)ei + kg * 384 + d16b;
            Bn[0] = *reinterpret_cast<const short8*>(pb + 0);
            Bn[1] = *reinterpret_cast<const short8*>(pb + 64);
            Bn[2] = *reinterpret_cast<const short8*>(pb + 128);
            Bn[3] = *reinterpret_cast<const short8*>(pb + 192);
            Bn[4] = *reinterpret_cast<const short8*>(pb + 256);
            Bn[5] = *reinterpret_cast<const short8*>(pb + 320);
            esqn = prec[kg];
        }

        f32x4 acc[4];
#pragma unroll
        for (int rf = 0; rf < 4; ++rf) acc[rf] = (f32x4){0.f, 0.f, 0.f, 0.f};

        // pass order identical to r9/r15: per dstep: (zh,eh),(zh,em),(zh,el),(zm,eh),(zm,em),(zl,eh)
#pragma unroll
        for (int ds = 0; ds < 2; ++ds) {
#pragma unroll
            for (int rf = 0; rf < 4; ++rf)
                acc[rf] = __builtin_amdgcn_mfma_f32_16x16x32_bf16(A[0][ds][rf], Bc[0 * 2 + ds], acc[rf], 0, 0, 0);
#pragma unroll
            for (int rf = 0; rf < 4; ++rf)
                acc[rf] = __builtin_amdgcn_mfma_f32_16x16x32_bf16(A[0][ds][rf], Bc[1 * 2 + ds], acc[rf], 0, 0, 0);
#pragma unroll
            for (int rf = 0; rf < 4; ++rf)
                acc[rf] = __builtin_amdgcn_mfma_f32_16x16x32_bf16(A[0][ds][rf], Bc[2 * 2 + ds], acc[rf], 0, 0, 0);
#pragma unroll
            for (int rf = 0; rf < 4; ++rf)
                acc[rf] = __builtin_amdgcn_mfma_f32_16x16x32_bf16(A[1][ds][rf], Bc[0 * 2 + ds], acc[rf], 0, 0, 0);
#pragma unroll
            for (int rf = 0; rf < 4; ++rf)
                acc[rf] = __builtin_amdgcn_mfma_f32_16x16x32_bf16(A[1][ds][rf], Bc[1 * 2 + ds], acc[rf], 0, 0, 0);
#pragma unroll
            for (int rf = 0; rf < 4; ++rf)
                acc[rf] = __builtin_amdgcn_mfma_f32_16x16x32_bf16(A[2][ds][rf], Bc[0 * 2 + ds], acc[rf], 0, 0, 0);
        }

        // epilogue: score + running argmin (this lane's k = kglob for all 16 C-slots)
        const int kglob = kt * 64 + w * 16 + kl;
#pragma unroll
        for (int rf = 0; rf < 4; ++rf)
#pragma unroll
            for (int j = 0; j < 4; ++j) {
                const float t1 = zsq_r[rf * 4 + j] + esqc;       // round(zsq+esq)
                const float s = fmaf(-2.f, acc[rf][j], t1);      // round(t1-2dot)
                if (s < bestv[rf * 4 + j]) { bestv[rf * 4 + j] = s; besti[rf * 4 + j] = kglob; }
            }

        if (kt + 1 < NKT) {
#pragma unroll
            for (int i = 0; i < 6; ++i) Bc[i] = Bn[i];
            esqc = esqn;
        }
    }

    // ---- in-wave reduce over the 16 k-slots (lane&15) per row, tie -> lower k
#pragma unroll
    for (int i = 0; i < 16; ++i) {
#pragma unroll
        for (int m = 1; m < 16; m <<= 1) {
            const float ov = __shfl_xor(bestv[i], m, 16);
            const int   oi = __shfl_xor(besti[i], m, 16);
            if (ov < bestv[i] || (ov == bestv[i] && oi < besti[i])) {
                bestv[i] = ov; besti[i] = oi;
            }
        }
    }
    if ((lane & 15) == 0) {
#pragma unroll
        for (int rf = 0; rf < 4; ++rf)
#pragma unroll
            for (int j = 0; j < 4; ++j) {
                const int row = rf * 16 + (lane >> 4) * 4 + j;
                red_v[w][row] = bestv[rf * 4 + j];
                red_i[w][row] = besti[rf * 4 + j];
            }
    }
    __syncthreads();
    if (tid < 64) {
        float bv = red_v[0][tid];
        int   bi = red_i[0][tid];
#pragma unroll
        for (int s2 = 1; s2 < 4; ++s2) {
            const float v = red_v[s2][tid];
            const int   i = red_i[s2][tid];
            if (v < bv || (v == bv && i < bi)) { bv = v; bi = i; }
        }
        codes_lds[tid] = bi;
        out[row0 + tid] = (float)bi;
    }
    __syncthreads();

    // ---- fused quant + loss tail ----
    // thread (tt, dg): row tt, dims d = dg*16 .. dg*16+15
    {
        const int tt = tid & 63;
        const int dg = tid >> 6;
        const int code = codes_lds[tt];
        const float4* crow = reinterpret_cast<const float4*>(cb + (size_t)code * Dd + dg * 16);
        float4 q4[4];
#pragma unroll
        for (int i = 0; i < 4; ++i) q4[i] = crow[i];
        const float qf[16] = {q4[0].x, q4[0].y, q4[0].z, q4[0].w,
                              q4[1].x, q4[1].y, q4[1].z, q4[1].w,
                              q4[2].x, q4[2].y, q4[2].z, q4[2].w,
                              q4[3].x, q4[3].y, q4[3].z, q4[3].w};
        float* obase = out + OUT_Q_OFF + (size_t)b * (Dd * Tt) + (size_t)(dg * 16) * Tt + (t0 + tt);
        float lacc = 0.f;
#pragma unroll
        for (int g = 0; g < 2; ++g) {
            const int sw = tt * 128 + ((dg * 32 + g * 16) ^ ((tt & 7) << 4));
            const short8 zh8 = *reinterpret_cast<const short8*>((char*)z_lds + 0 * 8192 + sw);
            const short8 zm8 = *reinterpret_cast<const short8*>((char*)z_lds + 1 * 8192 + sw);
            const short8 zl8 = *reinterpret_cast<const short8*>((char*)z_lds + 2 * 8192 + sw);
#pragma unroll
            for (int j = 0; j < 8; ++j) {
                // z reconstructed from its 3-way split: err <= 2^-27|z| (loss-only)
                const float zv = (bf16f((ushort)zh8[j]) + bf16f((ushort)zm8[j])) + bf16f((ushort)zl8[j]);
                const float qv = qf[g * 8 + j];
                const float diff = qv - zv;
                lacc = fmaf(diff, diff, lacc);
                obase[(size_t)(g * 8 + j) * Tt] = qv;   // exact fp32 codebook value
            }
        }
        // block reduce 256 -> 1 (reuse zsq_part as flat float[256])
        float* red256 = &zsq_part[0][0];
        red256[tid] = lacc;
        __syncthreads();
#pragma unroll
        for (int s = 128; s > 0; s >>= 1) {
            if (tid < s) red256[tid] += red256[tid + s];
            __syncthreads();
        }
        if (tid == 0) partials[blockIdx.x] = red256[0];
    }
}

// ---------------- Kernel C: final loss reduce (1024 partials) ----------------
__global__ void __launch_bounds__(256) loss_kernel(const float* __restrict__ partials,
                                                   float* __restrict__ out) {
    __shared__ float red[256];
    const int t = threadIdx.x;
    red[t] = ((partials[t] + partials[t + 256]) + partials[t + 512]) + partials[t + 768];
    __syncthreads();
#pragma unroll
    for (int s = 128; s > 0; s >>= 1) {
        if (t < s) red[t] += red[t + s];
        __syncthreads();
    }
    if (t == 0)
        out[OUT_LOSS_OFF] = red[0] * (1.0f / (float)NTOT);
}

extern "C" void kernel_launch(void* const* d_in, const int* in_sizes, int n_in,
                              void* d_out, int out_size, void* d_ws, size_t ws_size,
                              hipStream_t stream) {
    const float* z = (const float*)d_in[0];
    const float* cb = (const float*)d_in[1];
    float* out = (float*)d_out;

    char* ws = (char*)d_ws;
    float* prec = (float*)(ws + WS_PREC_OFF);
    float* partials = (float*)(ws + WS_PART_OFF);
    ushort* ei = (ushort*)(ws + WS_EI_OFF);

    prep_kernel<<<Kk / 256, 256, 0, stream>>>(cb, prec, ei);
    mfma_argmin_kernel<<<BT / TM, 256, 0, stream>>>(z, cb, ei, prec, out, partials);
    loss_kernel<<<1, 256, 0, stream>>>(partials, out);
}